// Round 7
// baseline (352.825 us; speedup 1.0000x reference)
//
#include <hip/hip_runtime.h>
#include <hip/hip_bf16.h>
#include <stdint.h>

#define BATCH   2048
#define NIN     2048
#define NGATES  8192
#define NCOL    16384   // NGATES*2

typedef short s16x8 __attribute__((ext_vector_type(8)));   // 8 bf16 (4 VGPRs)
typedef float f32x4 __attribute__((ext_vector_type(4)));

__device__ __forceinline__ void gload_lds16(const void* g, void* l) {
  __builtin_amdgcn_global_load_lds(
      (const __attribute__((address_space(1))) void*)g,
      (__attribute__((address_space(3))) void*)l,
      16, 0, 0);
}

__device__ __forceinline__ unsigned short f2bf(float f) {
  __hip_bfloat16 h = __float2bfloat16(f);
  return __builtin_bit_cast(unsigned short, h);
}
__device__ __forceinline__ float bf2f(unsigned int u) {
  return __bfloat162float(__builtin_bit_cast(__hip_bfloat16,
                                             (unsigned short)(u & 0xffff)));
}

// ---------------------------------------------------------------------------
// Kernel 1 (merged): blocks 0..4095: x fp32 -> bf16 row-major.
//                    blocks 4096..4127: per-gate bilinear coeffs from
//                    softmax(w[:,g]):  out = P0 + P1*A + P2*B + P3*A*B.
// ---------------------------------------------------------------------------
__global__ __launch_bounds__(256) void pre_k(const float4* __restrict__ x,
                                             ushort4* __restrict__ xb,
                                             const float* __restrict__ w,
                                             float4* __restrict__ coeff) {
  const int b = blockIdx.x;
  const int t = threadIdx.x;
  if (b < 4096) {
    const int i = b * 256 + t;
    float4 v = x[i];
    ushort4 h;
    h.x = f2bf(v.x); h.y = f2bf(v.y); h.z = f2bf(v.z); h.w = f2bf(v.w);
    xb[i] = h;
  } else {
    const int g = (b - 4096) * 256 + t;
    float e[16];
    float s = 0.f;
#pragma unroll
    for (int k = 0; k < 16; ++k) { e[k] = __expf(w[k * NGATES + g]); s += e[k]; }
    const float inv = 1.0f / s;
#pragma unroll
    for (int k = 0; k < 16; ++k) e[k] *= inv;
    const float P0 = e[8] + e[9] + e[10] + e[11] + e[12] + e[13] + e[14] + e[15];
    const float P1 = e[2] + e[3] + e[6] + e[7] - e[8] - e[9] - e[12] - e[13];
    const float P2 = e[4] + e[5] + e[6] + e[7] - e[8] - e[9] - e[10] - e[11];
    const float P3 = e[1] - e[2] - e[4] - 2.f * e[6] - e[7] + e[8] + 2.f * e[9]
                   + e[11] + e[13] - e[14];
    coeff[g] = make_float4(P0, P1, P2, P3);
  }
}

// ---------------------------------------------------------------------------
// Kernel 2 (v4, unchanged): e = exp(c) bf16 transposed to bT[n][k].
// [512 n x 64 k] tile, 1KB-contiguous reads, 128B-contiguous stores.
// Col partial sums per 64k-chunk -> psums[32][NCOL]; inv_k folds.
// Grid (32, 32). Dyn LDS 69664B.
// ---------------------------------------------------------------------------
__global__ __launch_bounds__(256) void softmax_t_k(const float* __restrict__ c,
                                                   unsigned short* __restrict__ bT,
                                                   float* __restrict__ psums) {
  extern __shared__ char sm4[];                 // 65536 tile + 4128 red
  char*  tile = sm4;                            // [512 cols][128 B]
  float* red  = (float*)(sm4 + 65536);          // [2][516]
  const int t  = threadIdx.x;
  const int ng = (t & 127) * 4;   // 4 consecutive cols within 512-chunk
  const int kg = t >> 7;          // 0..1: 8-row half
  const int n0 = blockIdx.x * 512;
  const int k0 = blockIdx.y * 64;
  const float* cb = c + (size_t)n0 + ng;
  float s0 = 0.f, s1 = 0.f, s2 = 0.f, s3 = 0.f;

  float4 v[8], nv[8];
  {
    const int r0 = k0 + kg * 8;
#pragma unroll
    for (int d = 0; d < 8; ++d)
      v[d] = *(const float4*)&cb[(size_t)(r0 + d) * NCOL];
  }
  for (int it = 0; it < 4; ++it) {
    if (it < 3) {
      const int r1 = k0 + (it + 1) * 16 + kg * 8;
#pragma unroll
      for (int d = 0; d < 8; ++d)
        nv[d] = *(const float4*)&cb[(size_t)(r1 + d) * NCOL];
    }
    unsigned int u[4][4];   // [col][k-pair]
#pragma unroll
    for (int d2 = 0; d2 < 4; ++d2) {
      float4 e0 = v[2 * d2], e1 = v[2 * d2 + 1];
      unsigned int a0 = f2bf(__expf(e0.x)), b0 = f2bf(__expf(e1.x));
      unsigned int a1 = f2bf(__expf(e0.y)), b1 = f2bf(__expf(e1.y));
      unsigned int a2 = f2bf(__expf(e0.z)), b2 = f2bf(__expf(e1.z));
      unsigned int a3 = f2bf(__expf(e0.w)), b3 = f2bf(__expf(e1.w));
      s0 += bf2f(a0) + bf2f(b0);
      s1 += bf2f(a1) + bf2f(b1);
      s2 += bf2f(a2) + bf2f(b2);
      s3 += bf2f(a3) + bf2f(b3);
      u[0][d2] = a0 | (b0 << 16);
      u[1][d2] = a1 | (b1 << 16);
      u[2][d2] = a2 | (b2 << 16);
      u[3][d2] = a3 | (b3 << 16);
    }
    // chunk of 4 k-pairs (16B) within the 64k row: it*2 + kg (0..7)
    const int chunk = it * 2 + kg;
    const int sw    = (chunk ^ (t & 7)) * 16;   // (col>>2)&7 == t&7 for all j
#pragma unroll
    for (int j = 0; j < 4; ++j) {
      uint4 pk = make_uint4(u[j][0], u[j][1], u[j][2], u[j][3]);
      *(uint4*)&tile[(ng + j) * 128 + sw] = pk;
    }
    if (it < 3) {
#pragma unroll
      for (int d = 0; d < 8; ++d) v[d] = nv[d];
    }
  }
  red[kg * 516 + ng + 0] = s0;
  red[kg * 516 + ng + 1] = s1;
  red[kg * 516 + ng + 2] = s2;
  red[kg * 516 + ng + 3] = s3;
  __syncthreads();

  // Phase 2: 8 lanes per bT row, 128B contiguous stores. 16 passes x 32 rows.
  {
    const int rsub = t >> 3;            // 0..31: row within pass
    const int ch   = t & 7;             // 16B chunk
#pragma unroll
    for (int p = 0; p < 16; ++p) {
      const int row = p * 32 + rsub;
      const int sw  = (ch ^ ((row >> 2) & 7)) * 16;
      uint4 vv = *(const uint4*)&tile[row * 128 + sw];
      *(uint4*)&bT[(size_t)(n0 + row) * NIN + k0 + ch * 8] = vv;
    }
  }
  // column partial sums for this 64k chunk
  {
    const int c0 = 2 * t;
    const float2 tot = make_float2(
        red[c0] + red[516 + c0], red[c0 + 1] + red[516 + c0 + 1]);
    *(float2*)&psums[(size_t)blockIdx.y * NCOL + n0 + c0] = tot;
  }
}

// ---------------------------------------------------------------------------
// Kernel 3: fold 32 k-chunk partials -> invs[n] = 1/sum
// ---------------------------------------------------------------------------
__global__ __launch_bounds__(256) void inv_k(const float* __restrict__ psums,
                                             float* __restrict__ invs) {
  const int n = blockIdx.x * 256 + threadIdx.x;
  float s = 0.f;
#pragma unroll
  for (int q = 0; q < 32; ++q) s += psums[(size_t)q * NCOL + n];
  invs[n] = 1.0f / s;
}

// ---------------------------------------------------------------------------
// Kernel 4: 256x256-tile bf16 MFMA GEMM — MERGED 2-PHASE K-loop.
// Round-6 post-mortem: per-phase overhead ~616cyc (2 barriers + lgkm drain)
// vs ~310cyc per-wave MFMA -> 43% MfmaUtil. This version halves the sync:
// per K-tile, 2 phases x 32 MFMA instead of 4 x 16 (4 barriers, not 8).
//   P0: read A1(8)+B1(4)+B2(4) ds_b128; issue A2(kt+1) [other buf - safe];
//       bar; lgkm0; 32 MFMA (i0-3 x j0-3); bar
//   P1: read A2(8); issue A1/B1/B2(kt+2) [curr buf - safe only AFTER P0's
//       barrier proves all waves' reads of those regions completed];
//       bar; lgkm0; 32 MFMA (i4-7 x j0-3); vmcnt(6); bar
// FIFO invariant preserved: end-of-kt vmcnt(6) leaves exactly A1/B1/B2(kt+2)
// (6 loads) in flight, draining through A2(kt+1) -> tile kt+1 resident.
// Same af[8]/bfr[8] live set -> no new register pressure (spill tripwire:
// WRITE_SIZE must stay ~98MB, VGPR ~116).
// ---------------------------------------------------------------------------
#define MFMA_B16(a, b, c) __builtin_amdgcn_mfma_f32_16x16x32_bf16(a, b, c, 0, 0, 0)

__global__ __launch_bounds__(512, 2) void gemm_gate_k(
    const unsigned short* __restrict__ xb,   // [2048][2048] bf16
    const unsigned short* __restrict__ bT,   // [16384][2048] bf16
    const float* __restrict__ invs,          // [16384]
    const float4* __restrict__ coeff,        // [8192]
    float* __restrict__ out) {               // [2048][8192]
  extern __shared__ char smem[];             // 131072 B
  constexpr int NT = 32;                     // K / BK = 2048/64

  const int t  = threadIdx.x;                // 0..511
  const int l  = t & 63;
  const int w  = t >> 6;
  const int wm = w >> 2;                     // 0..1: M half
  const int wn = w & 3;                      // 0..3: N quarter
  const int fr = l & 15;
  const int cq = l >> 4;

  // XCD-bijective swizzle (512 % 8 == 0)
  const int bid = blockIdx.x;
  const int xcd = bid & 7;
  const int loc = bid >> 3;                  // 0..63
  const int m0  = (loc & 7) * 256;
  const int g0  = (xcd * 8 + (loc >> 3)) * 128;

  // ---- stage source offsets (elements), inverse-XOR-swizzled + B-permuted
  uint32_t offA[2][2], offB[2][2];           // [unit][round]
#pragma unroll
  for (int r = 0; r < 2; ++r) {
    const int idx = r * 512 + t;             // 0..1023 -> lds (row, slot)
    const int lr  = idx >> 3;
    const int ch  = (idx & 7) ^ (lr & 7);    // chunk stored at this slot
    const int rA  = (lr & 63) + ((lr >> 6) << 7);       // A1: rows 0-63,128-191
    offA[0][r] = (uint32_t)(m0 + rA) * NIN + ch * 8;
    offA[1][r] = offA[0][r] + (uint32_t)64 * NIN;       // A2: +64
    offB[0][r] = (uint32_t)(2 * (g0 + lr)) * NIN + ch * 8;  // even col
    offB[1][r] = offB[0][r] + NIN;                          // odd col
  }

  auto issueA = [&](int u, int kt) {
    char* d = smem + ((kt & 1) << 16) + (u << 14) + t * 16;
    gload_lds16(xb + offA[u][0] + kt * 64, d);
    gload_lds16(xb + offA[u][1] + kt * 64, d + 8192);
  };
  auto issueB = [&](int u, int kt) {
    char* d = smem + ((kt & 1) << 16) + ((2 + u) << 14) + t * 16;
    gload_lds16(bT + offB[u][0] + kt * 64, d);
    gload_lds16(bT + offB[u][1] + kt * 64, d + 8192);
  };

  // ---- fragment read offsets (row*128, slot = chunk ^ (row&7))
  const int aob = (wm * 64 + fr) * 128;          // + unit*16384 + i*2048
  const int bob = 32768 + (wn * 32 + fr) * 128;  // + unit*16384 + j*2048
  const int sx0 = ((cq)     ^ (fr & 7)) * 16;    // ks=0 slot
  const int sx1 = ((cq + 4) ^ (fr & 7)) * 16;    // ks=1 slot

  f32x4 acc[8][4] = {};
  s16x8 af[8];     // current A half: 4 i x 2 ks
  s16x8 bfr[8];    // [0..3]=B1 (j=0,1 x ks), [4..7]=B2 (j=2,3 x ks)

  // ---- prologue: tile0 full + tile1 {A1,B1,B2}; A2(1) comes at kt=0 P0
  issueA(0, 0); issueA(1, 0); issueB(0, 0); issueB(1, 0);
  issueA(0, 1); issueB(0, 1); issueB(1, 1);
  asm volatile("s_waitcnt vmcnt(6)" ::: "memory");   // tile0 landed
  asm volatile("s_barrier" ::: "memory");

  for (int kt = 0; kt < NT; ++kt) {
    char* rb = smem + ((kt & 1) << 16);

    // ===== P0: read A1 + B1 + B2 (16 ds_b128); issue A2(kt+1);
    //           32 MFMA: (i0-3) x (j0-3)
#pragma unroll
    for (int i = 0; i < 4; ++i) {
      af[i * 2 + 0] = *(const s16x8*)(rb + aob + i * 2048 + sx0);
      af[i * 2 + 1] = *(const s16x8*)(rb + aob + i * 2048 + sx1);
    }
#pragma unroll
    for (int j = 0; j < 2; ++j) {
      bfr[j * 2 + 0] = *(const s16x8*)(rb + bob + j * 2048 + sx0);
      bfr[j * 2 + 1] = *(const s16x8*)(rb + bob + j * 2048 + sx1);
      bfr[4 + j * 2 + 0] = *(const s16x8*)(rb + bob + 16384 + j * 2048 + sx0);
      bfr[4 + j * 2 + 1] = *(const s16x8*)(rb + bob + 16384 + j * 2048 + sx1);
    }
    if (kt + 1 < NT) issueA(1, kt + 1);
    asm volatile("s_barrier" ::: "memory");
    asm volatile("s_waitcnt lgkmcnt(0)" ::: "memory");
    __builtin_amdgcn_s_setprio(1);
#pragma unroll
    for (int i = 0; i < 4; ++i) {
#pragma unroll
      for (int j = 0; j < 2; ++j) {
        acc[i][j] = MFMA_B16(af[i * 2 + 0], bfr[j * 2 + 0], acc[i][j]);
        acc[i][j] = MFMA_B16(af[i * 2 + 1], bfr[j * 2 + 1], acc[i][j]);
        acc[i][2 + j] = MFMA_B16(af[i * 2 + 0], bfr[4 + j * 2 + 0], acc[i][2 + j]);
        acc[i][2 + j] = MFMA_B16(af[i * 2 + 1], bfr[4 + j * 2 + 1], acc[i][2 + j]);
      }
    }
    __builtin_amdgcn_s_setprio(0);
    asm volatile("s_barrier" ::: "memory");

    // ===== P1: read A2 (8 ds_b128); issue A1/B1/B2(kt+2);
    //           32 MFMA: (i4-7) x (j0-3); counted vmcnt at K-tile end
#pragma unroll
    for (int i = 0; i < 4; ++i) {
      af[i * 2 + 0] = *(const s16x8*)(rb + 16384 + aob + i * 2048 + sx0);
      af[i * 2 + 1] = *(const s16x8*)(rb + 16384 + aob + i * 2048 + sx1);
    }
    if (kt + 2 < NT) {
      issueA(0, kt + 2); issueB(0, kt + 2); issueB(1, kt + 2);
    }
    asm volatile("s_barrier" ::: "memory");
    asm volatile("s_waitcnt lgkmcnt(0)" ::: "memory");
    __builtin_amdgcn_s_setprio(1);
#pragma unroll
    for (int i = 0; i < 4; ++i) {
#pragma unroll
      for (int j = 0; j < 2; ++j) {
        acc[4 + i][j] = MFMA_B16(af[i * 2 + 0], bfr[j * 2 + 0], acc[4 + i][j]);
        acc[4 + i][j] = MFMA_B16(af[i * 2 + 1], bfr[j * 2 + 1], acc[4 + i][j]);
        acc[4 + i][2 + j] = MFMA_B16(af[i * 2 + 0], bfr[4 + j * 2 + 0], acc[4 + i][2 + j]);
        acc[4 + i][2 + j] = MFMA_B16(af[i * 2 + 1], bfr[4 + j * 2 + 1], acc[4 + i][2 + j]);
      }
    }
    __builtin_amdgcn_s_setprio(0);
    if (kt < NT - 2) {
      asm volatile("s_waitcnt vmcnt(6)" ::: "memory");  // tile kt+1 resident
    } else {
      asm volatile("s_waitcnt vmcnt(0)" ::: "memory");  // drain tail
    }
    asm volatile("s_barrier" ::: "memory");
  }

  // ---- epilogue: normalize (precomputed invs), bilinear gate, store.
#pragma unroll
  for (int j = 0; j < 2; ++j) {
    const int gate = g0 + wn * 32 + j * 16 + fr;
    const float2 iv = *(const float2*)&invs[2 * gate];
    const float4 P  = coeff[gate];
#pragma unroll
    for (int i = 0; i < 8; ++i) {
#pragma unroll
      for (int r = 0; r < 4; ++r) {
        const float A = acc[i][j][r]     * iv.x;
        const float B = acc[i][j + 2][r] * iv.y;
        const float res = P.x + P.y * A + P.z * B + P.w * A * B;
        const int m = m0 + wm * 128 + i * 16 + cq * 4 + r;
        out[(size_t)m * NGATES + gate] = res;
      }
    }
  }
}

// ---------------------------------------------------------------------------
extern "C" void kernel_launch(void* const* d_in, const int* in_sizes, int n_in,
                              void* d_out, int out_size, void* d_ws,
                              size_t ws_size, hipStream_t stream) {
  const float* x = (const float*)d_in[0];   // [2048][2048]
  const float* w = (const float*)d_in[1];   // [16][8192]
  const float* c = (const float*)d_in[2];   // [2048][8192][2]
  float* out = (float*)d_out;               // [2048][8192]
  char* ws = (char*)d_ws;

  unsigned short* xb  = (unsigned short*)(ws);              // 8,388,608 B
  unsigned short* bT  = (unsigned short*)(ws + 8388608);    // 67,108,864 B
  float*          psv = (float*)(ws + 75497472);            // 2,097,152 B
  float*          ivv = (float*)(ws + 77594624);            // 65,536 B
  float4*         cf  = (float4*)(ws + 77660160);           // 131,072 B

  static bool attr_done = false;
  if (!attr_done) {
    (void)hipFuncSetAttribute(reinterpret_cast<const void*>(gemm_gate_k),
                              hipFuncAttributeMaxDynamicSharedMemorySize,
                              131072);
    (void)hipFuncSetAttribute(reinterpret_cast<const void*>(softmax_t_k),
                              hipFuncAttributeMaxDynamicSharedMemorySize,
                              69664);
    attr_done = true;
  }

  pre_k<<<4128, 256, 0, stream>>>((const float4*)x, (ushort4*)xb, w, cf);
  dim3 sg(NCOL / 512, NIN / 64);
  softmax_t_k<<<sg, 256, 69664, stream>>>(c, bT, psv);
  inv_k<<<NCOL / 256, 256, 0, stream>>>(psv, ivv);
  gemm_gate_k<<<512, 512, 131072, stream>>>(xb, bT, ivv, cf, out);
}

// Round 8
// 337.971 us; speedup vs baseline: 1.0440x; 1.0440x over previous
//
#include <hip/hip_runtime.h>
#include <hip/hip_bf16.h>
#include <stdint.h>

#define BATCH   2048
#define NIN     2048
#define NGATES  8192
#define NCOL    16384   // NGATES*2

typedef short s16x8 __attribute__((ext_vector_type(8)));   // 8 bf16 (4 VGPRs)
typedef float f32x4 __attribute__((ext_vector_type(4)));

__device__ __forceinline__ void gload_lds16(const void* g, void* l) {
  __builtin_amdgcn_global_load_lds(
      (const __attribute__((address_space(1))) void*)g,
      (__attribute__((address_space(3))) void*)l,
      16, 0, 0);
}

__device__ __forceinline__ unsigned short f2bf(float f) {
  __hip_bfloat16 h = __float2bfloat16(f);
  return __builtin_bit_cast(unsigned short, h);
}
__device__ __forceinline__ float bf2f(unsigned int u) {
  return __bfloat162float(__builtin_bit_cast(__hip_bfloat16,
                                             (unsigned short)(u & 0xffff)));
}

// ---------------------------------------------------------------------------
// Kernel 1 (merged): blocks 0..4095: x fp32 -> bf16 row-major.
//                    blocks 4096..4127: per-gate bilinear coeffs from
//                    softmax(w[:,g]):  out = P0 + P1*A + P2*B + P3*A*B.
// ---------------------------------------------------------------------------
__global__ __launch_bounds__(256) void pre_k(const float4* __restrict__ x,
                                             ushort4* __restrict__ xb,
                                             const float* __restrict__ w,
                                             float4* __restrict__ coeff) {
  const int b = blockIdx.x;
  const int t = threadIdx.x;
  if (b < 4096) {
    const int i = b * 256 + t;
    float4 v = x[i];
    ushort4 h;
    h.x = f2bf(v.x); h.y = f2bf(v.y); h.z = f2bf(v.z); h.w = f2bf(v.w);
    xb[i] = h;
  } else {
    const int g = (b - 4096) * 256 + t;
    float e[16];
    float s = 0.f;
#pragma unroll
    for (int k = 0; k < 16; ++k) { e[k] = __expf(w[k * NGATES + g]); s += e[k]; }
    const float inv = 1.0f / s;
#pragma unroll
    for (int k = 0; k < 16; ++k) e[k] *= inv;
    const float P0 = e[8] + e[9] + e[10] + e[11] + e[12] + e[13] + e[14] + e[15];
    const float P1 = e[2] + e[3] + e[6] + e[7] - e[8] - e[9] - e[12] - e[13];
    const float P2 = e[4] + e[5] + e[6] + e[7] - e[8] - e[9] - e[10] - e[11];
    const float P3 = e[1] - e[2] - e[4] - 2.f * e[6] - e[7] + e[8] + 2.f * e[9]
                   + e[11] + e[13] - e[14];
    coeff[g] = make_float4(P0, P1, P2, P3);
  }
}

// ---------------------------------------------------------------------------
// Kernel 2 (v4, unchanged): e = exp(c) bf16 transposed to bT[n][k].
// [512 n x 64 k] tile, 1KB-contiguous reads, 128B-contiguous stores.
// Col partial sums per 64k-chunk -> psums[32][NCOL]; inv_k folds.
// Grid (32, 32). Dyn LDS 69664B.
// ---------------------------------------------------------------------------
__global__ __launch_bounds__(256) void softmax_t_k(const float* __restrict__ c,
                                                   unsigned short* __restrict__ bT,
                                                   float* __restrict__ psums) {
  extern __shared__ char sm4[];                 // 65536 tile + 4128 red
  char*  tile = sm4;                            // [512 cols][128 B]
  float* red  = (float*)(sm4 + 65536);          // [2][516]
  const int t  = threadIdx.x;
  const int ng = (t & 127) * 4;   // 4 consecutive cols within 512-chunk
  const int kg = t >> 7;          // 0..1: 8-row half
  const int n0 = blockIdx.x * 512;
  const int k0 = blockIdx.y * 64;
  const float* cb = c + (size_t)n0 + ng;
  float s0 = 0.f, s1 = 0.f, s2 = 0.f, s3 = 0.f;

  float4 v[8], nv[8];
  {
    const int r0 = k0 + kg * 8;
#pragma unroll
    for (int d = 0; d < 8; ++d)
      v[d] = *(const float4*)&cb[(size_t)(r0 + d) * NCOL];
  }
  for (int it = 0; it < 4; ++it) {
    if (it < 3) {
      const int r1 = k0 + (it + 1) * 16 + kg * 8;
#pragma unroll
      for (int d = 0; d < 8; ++d)
        nv[d] = *(const float4*)&cb[(size_t)(r1 + d) * NCOL];
    }
    unsigned int u[4][4];   // [col][k-pair]
#pragma unroll
    for (int d2 = 0; d2 < 4; ++d2) {
      float4 e0 = v[2 * d2], e1 = v[2 * d2 + 1];
      unsigned int a0 = f2bf(__expf(e0.x)), b0 = f2bf(__expf(e1.x));
      unsigned int a1 = f2bf(__expf(e0.y)), b1 = f2bf(__expf(e1.y));
      unsigned int a2 = f2bf(__expf(e0.z)), b2 = f2bf(__expf(e1.z));
      unsigned int a3 = f2bf(__expf(e0.w)), b3 = f2bf(__expf(e1.w));
      s0 += bf2f(a0) + bf2f(b0);
      s1 += bf2f(a1) + bf2f(b1);
      s2 += bf2f(a2) + bf2f(b2);
      s3 += bf2f(a3) + bf2f(b3);
      u[0][d2] = a0 | (b0 << 16);
      u[1][d2] = a1 | (b1 << 16);
      u[2][d2] = a2 | (b2 << 16);
      u[3][d2] = a3 | (b3 << 16);
    }
    // chunk of 4 k-pairs (16B) within the 64k row: it*2 + kg (0..7)
    const int chunk = it * 2 + kg;
    const int sw    = (chunk ^ (t & 7)) * 16;   // (col>>2)&7 == t&7 for all j
#pragma unroll
    for (int j = 0; j < 4; ++j) {
      uint4 pk = make_uint4(u[j][0], u[j][1], u[j][2], u[j][3]);
      *(uint4*)&tile[(ng + j) * 128 + sw] = pk;
    }
    if (it < 3) {
#pragma unroll
      for (int d = 0; d < 8; ++d) v[d] = nv[d];
    }
  }
  red[kg * 516 + ng + 0] = s0;
  red[kg * 516 + ng + 1] = s1;
  red[kg * 516 + ng + 2] = s2;
  red[kg * 516 + ng + 3] = s3;
  __syncthreads();

  // Phase 2: 8 lanes per bT row, 128B contiguous stores. 16 passes x 32 rows.
  {
    const int rsub = t >> 3;            // 0..31: row within pass
    const int ch   = t & 7;             // 16B chunk
#pragma unroll
    for (int p = 0; p < 16; ++p) {
      const int row = p * 32 + rsub;
      const int sw  = (ch ^ ((row >> 2) & 7)) * 16;
      uint4 vv = *(const uint4*)&tile[row * 128 + sw];
      *(uint4*)&bT[(size_t)(n0 + row) * NIN + k0 + ch * 8] = vv;
    }
  }
  // column partial sums for this 64k chunk
  {
    const int c0 = 2 * t;
    const float2 tot = make_float2(
        red[c0] + red[516 + c0], red[c0 + 1] + red[516 + c0 + 1]);
    *(float2*)&psums[(size_t)blockIdx.y * NCOL + n0 + c0] = tot;
  }
}

// ---------------------------------------------------------------------------
// Kernel 3: fold 32 k-chunk partials -> invs[n] = 1/sum
// ---------------------------------------------------------------------------
__global__ __launch_bounds__(256) void inv_k(const float* __restrict__ psums,
                                             float* __restrict__ invs) {
  const int n = blockIdx.x * 256 + threadIdx.x;
  float s = 0.f;
#pragma unroll
  for (int q = 0; q < 32; ++q) s += psums[(size_t)q * NCOL + n];
  invs[n] = 1.0f / s;
}

// ---------------------------------------------------------------------------
// Kernel 4: 256x256-tile 8-phase bf16 MFMA GEMM — round-3 4-phase body
// (proven 132.6us, VGPR 116, 0 spills) with the 4 OPENING barriers removed.
// Hazard re-derivation (round-8): every WAR (stage-issue over a region other
// waves read) is separated by a CLOSING barrier of an earlier phase; RAW
// gload->ds_read is carried by end-of-tile vmcnt(6)+barrier. The opening
// barriers only enforced lockstep MFMA entry — removing them halves the
// rendezvous count (4/tile vs 8) while keeping the 16-MFMA clusters and
// 8-12-read bunches (m196: the fine interleave is the load-bearing part;
// round-7's 32-MFMA merge regressed). Per-wave lgkmcnt(0) still orders own
// ds_reads before own MFMAs; waves drift within a phase (one wave's MFMA
// overlaps another's ds_reads), resync at the closing barrier.
// ---------------------------------------------------------------------------
#define MFMA_B16(a, b, c) __builtin_amdgcn_mfma_f32_16x16x32_bf16(a, b, c, 0, 0, 0)

__global__ __launch_bounds__(512, 2) void gemm_gate_k(
    const unsigned short* __restrict__ xb,   // [2048][2048] bf16
    const unsigned short* __restrict__ bT,   // [16384][2048] bf16
    const float* __restrict__ invs,          // [16384]
    const float4* __restrict__ coeff,        // [8192]
    float* __restrict__ out) {               // [2048][8192]
  extern __shared__ char smem[];             // 131072 B
  constexpr int NT = 32;                     // K / BK = 2048/64

  const int t  = threadIdx.x;                // 0..511
  const int l  = t & 63;
  const int w  = t >> 6;
  const int wm = w >> 2;                     // 0..1: M half
  const int wn = w & 3;                      // 0..3: N quarter
  const int fr = l & 15;
  const int cq = l >> 4;

  // XCD-bijective swizzle (512 % 8 == 0)
  const int bid = blockIdx.x;
  const int xcd = bid & 7;
  const int loc = bid >> 3;                  // 0..63
  const int m0  = (loc & 7) * 256;
  const int g0  = (xcd * 8 + (loc >> 3)) * 128;

  // ---- stage source offsets (elements), inverse-XOR-swizzled + B-permuted
  uint32_t offA[2][2], offB[2][2];           // [unit][round]
#pragma unroll
  for (int r = 0; r < 2; ++r) {
    const int idx = r * 512 + t;             // 0..1023 -> lds (row, slot)
    const int lr  = idx >> 3;
    const int ch  = (idx & 7) ^ (lr & 7);    // chunk stored at this slot
    const int rA  = (lr & 63) + ((lr >> 6) << 7);       // A1: rows 0-63,128-191
    offA[0][r] = (uint32_t)(m0 + rA) * NIN + ch * 8;
    offA[1][r] = offA[0][r] + (uint32_t)64 * NIN;       // A2: +64
    offB[0][r] = (uint32_t)(2 * (g0 + lr)) * NIN + ch * 8;  // even col
    offB[1][r] = offB[0][r] + NIN;                          // odd col
  }

  auto issueA = [&](int u, int kt) {
    char* d = smem + ((kt & 1) << 16) + (u << 14) + t * 16;
    gload_lds16(xb + offA[u][0] + kt * 64, d);
    gload_lds16(xb + offA[u][1] + kt * 64, d + 8192);
  };
  auto issueB = [&](int u, int kt) {
    char* d = smem + ((kt & 1) << 16) + ((2 + u) << 14) + t * 16;
    gload_lds16(bT + offB[u][0] + kt * 64, d);
    gload_lds16(bT + offB[u][1] + kt * 64, d + 8192);
  };

  // ---- fragment read offsets (row*128, slot = chunk ^ (row&7))
  const int aob = (wm * 64 + fr) * 128;          // + unit*16384 + i*2048
  const int bob = 32768 + (wn * 32 + fr) * 128;  // + unit*16384 + j*2048
  const int sx0 = ((cq)     ^ (fr & 7)) * 16;    // ks=0 slot
  const int sx1 = ((cq + 4) ^ (fr & 7)) * 16;    // ks=1 slot

  f32x4 acc[8][4] = {};
  s16x8 af[8];     // current A half: 4 i x 2 ks
  s16x8 bfr[8];    // [0..3]=B1 (j=0,1 x ks), [4..7]=B2 (j=2,3 x ks)

  // ---- prologue: tile0 full + tile1 {A1,B1,B2}; A2(1) comes at kt=0 ph0
  issueA(0, 0); issueA(1, 0); issueB(0, 0); issueB(1, 0);
  issueA(0, 1); issueB(0, 1); issueB(1, 1);
  asm volatile("s_waitcnt vmcnt(6)" ::: "memory");   // tile0 landed
  asm volatile("s_barrier" ::: "memory");

  for (int kt = 0; kt < NT; ++kt) {
    char* rb = smem + ((kt & 1) << 16);

    // ===== phase 0: (i0-3, j0-1) — read A1 + B1, stage A2(kt+1)
#pragma unroll
    for (int i = 0; i < 4; ++i) {
      af[i * 2 + 0] = *(const s16x8*)(rb + aob + i * 2048 + sx0);
      af[i * 2 + 1] = *(const s16x8*)(rb + aob + i * 2048 + sx1);
    }
#pragma unroll
    for (int j = 0; j < 2; ++j) {
      bfr[j * 2 + 0] = *(const s16x8*)(rb + bob + j * 2048 + sx0);
      bfr[j * 2 + 1] = *(const s16x8*)(rb + bob + j * 2048 + sx1);
    }
    if (kt + 1 < NT) issueA(1, kt + 1);
    asm volatile("s_waitcnt lgkmcnt(0)" ::: "memory");
    __builtin_amdgcn_s_setprio(1);
#pragma unroll
    for (int i = 0; i < 4; ++i)
#pragma unroll
      for (int j = 0; j < 2; ++j) {
        acc[i][j] = MFMA_B16(af[i * 2 + 0], bfr[j * 2 + 0], acc[i][j]);
        acc[i][j] = MFMA_B16(af[i * 2 + 1], bfr[j * 2 + 1], acc[i][j]);
      }
    __builtin_amdgcn_s_setprio(0);
    asm volatile("s_barrier" ::: "memory");

    // ===== phase 1: (i0-3, j2-3) — read B2, stage A1(kt+2)
#pragma unroll
    for (int j = 0; j < 2; ++j) {
      bfr[4 + j * 2 + 0] = *(const s16x8*)(rb + bob + 16384 + j * 2048 + sx0);
      bfr[4 + j * 2 + 1] = *(const s16x8*)(rb + bob + 16384 + j * 2048 + sx1);
    }
    if (kt + 2 < NT) issueA(0, kt + 2);
    asm volatile("s_waitcnt lgkmcnt(0)" ::: "memory");
    __builtin_amdgcn_s_setprio(1);
#pragma unroll
    for (int i = 0; i < 4; ++i)
#pragma unroll
      for (int j = 0; j < 2; ++j) {
        acc[i][2 + j] = MFMA_B16(af[i * 2 + 0], bfr[4 + j * 2 + 0], acc[i][2 + j]);
        acc[i][2 + j] = MFMA_B16(af[i * 2 + 1], bfr[4 + j * 2 + 1], acc[i][2 + j]);
      }
    __builtin_amdgcn_s_setprio(0);
    asm volatile("s_barrier" ::: "memory");

    // ===== phase 2: (i4-7, j2-3) — read A2 into af, stage B1(kt+2)
#pragma unroll
    for (int i = 0; i < 4; ++i) {
      af[i * 2 + 0] = *(const s16x8*)(rb + 16384 + aob + i * 2048 + sx0);
      af[i * 2 + 1] = *(const s16x8*)(rb + 16384 + aob + i * 2048 + sx1);
    }
    if (kt + 2 < NT) issueB(0, kt + 2);
    asm volatile("s_waitcnt lgkmcnt(0)" ::: "memory");
    __builtin_amdgcn_s_setprio(1);
#pragma unroll
    for (int i = 0; i < 4; ++i)
#pragma unroll
      for (int j = 0; j < 2; ++j) {
        acc[4 + i][2 + j] = MFMA_B16(af[i * 2 + 0], bfr[4 + j * 2 + 0], acc[4 + i][2 + j]);
        acc[4 + i][2 + j] = MFMA_B16(af[i * 2 + 1], bfr[4 + j * 2 + 1], acc[4 + i][2 + j]);
      }
    __builtin_amdgcn_s_setprio(0);
    asm volatile("s_barrier" ::: "memory");

    // ===== phase 3: (i4-7, j0-1) — no reads, stage B2(kt+2), counted vmcnt
    if (kt + 2 < NT) issueB(1, kt + 2);
    __builtin_amdgcn_s_setprio(1);
#pragma unroll
    for (int i = 0; i < 4; ++i)
#pragma unroll
      for (int j = 0; j < 2; ++j) {
        acc[4 + i][j] = MFMA_B16(af[i * 2 + 0], bfr[j * 2 + 0], acc[4 + i][j]);
        acc[4 + i][j] = MFMA_B16(af[i * 2 + 1], bfr[j * 2 + 1], acc[4 + i][j]);
      }
    __builtin_amdgcn_s_setprio(0);
    if (kt < NT - 2) {
      asm volatile("s_waitcnt vmcnt(6)" ::: "memory");  // tile kt+1 resident
    } else {
      asm volatile("s_waitcnt vmcnt(0)" ::: "memory");  // drain tail
    }
    asm volatile("s_barrier" ::: "memory");
  }

  // ---- epilogue: normalize (precomputed invs), bilinear gate, store.
#pragma unroll
  for (int j = 0; j < 2; ++j) {
    const int gate = g0 + wn * 32 + j * 16 + fr;
    const float2 iv = *(const float2*)&invs[2 * gate];
    const float4 P  = coeff[gate];
#pragma unroll
    for (int i = 0; i < 8; ++i) {
#pragma unroll
      for (int r = 0; r < 4; ++r) {
        const float A = acc[i][j][r]     * iv.x;
        const float B = acc[i][j + 2][r] * iv.y;
        const float res = P.x + P.y * A + P.z * B + P.w * A * B;
        const int m = m0 + wm * 128 + i * 16 + cq * 4 + r;
        out[(size_t)m * NGATES + gate] = res;
      }
    }
  }
}

// ---------------------------------------------------------------------------
extern "C" void kernel_launch(void* const* d_in, const int* in_sizes, int n_in,
                              void* d_out, int out_size, void* d_ws,
                              size_t ws_size, hipStream_t stream) {
  const float* x = (const float*)d_in[0];   // [2048][2048]
  const float* w = (const float*)d_in[1];   // [16][8192]
  const float* c = (const float*)d_in[2];   // [2048][8192][2]
  float* out = (float*)d_out;               // [2048][8192]
  char* ws = (char*)d_ws;

  unsigned short* xb  = (unsigned short*)(ws);              // 8,388,608 B
  unsigned short* bT  = (unsigned short*)(ws + 8388608);    // 67,108,864 B
  float*          psv = (float*)(ws + 75497472);            // 2,097,152 B
  float*          ivv = (float*)(ws + 77594624);            // 65,536 B
  float4*         cf  = (float4*)(ws + 77660160);           // 131,072 B

  static bool attr_done = false;
  if (!attr_done) {
    (void)hipFuncSetAttribute(reinterpret_cast<const void*>(gemm_gate_k),
                              hipFuncAttributeMaxDynamicSharedMemorySize,
                              131072);
    (void)hipFuncSetAttribute(reinterpret_cast<const void*>(softmax_t_k),
                              hipFuncAttributeMaxDynamicSharedMemorySize,
                              69664);
    attr_done = true;
  }

  pre_k<<<4128, 256, 0, stream>>>((const float4*)x, (ushort4*)xb, w, cf);
  dim3 sg(NCOL / 512, NIN / 64);
  softmax_t_k<<<sg, 256, 69664, stream>>>(c, bT, psv);
  inv_k<<<NCOL / 256, 256, 0, stream>>>(psv, ivv);
  gemm_gate_k<<<512, 512, 131072, stream>>>(xb, bT, ivv, cf, out);
}